// Round 6
// baseline (538.105 us; speedup 1.0000x reference)
//
#include <hip/hip_runtime.h>
#include <hip/hip_bf16.h>

// GraphSAGE R6:
//  - sorted-gather: per-thread sort of the 16 neighbor ids clusters the
//    device-wide access pattern around a moving quantile -> L2/MALL-resident
//    (R5 counter evidence: 146 MB/layer of gather traffic reached HBM).
//  - B (weights, 64-131 KB, L2-resident) read directly from global in the
//    k-loop; no B LDS, k-loop barrier-free, LDS 75.8->34.8 KB, 3 blocks/CU.
//  - gemm1: full-K A staged once in LDS, barrier-free k-loop.
// Split-bf16 3-product GEMM (fp32-grade) throughout.

constexpr int N_NODES = 100000;
constexpr int FANOUT  = 16;

typedef __attribute__((ext_vector_type(8))) short short8;
typedef __attribute__((ext_vector_type(4))) float f32x4;

__device__ inline unsigned short bf16_rne(float f) {
    unsigned u = __float_as_uint(f);
    return (unsigned short)((u + 0x7fffu + ((u >> 16) & 1u)) >> 16);
}
__device__ inline float bf16_tof(unsigned short s) {
    return __uint_as_float(((unsigned)s) << 16);
}

// branchless odd-even transposition sort, 16 ints in registers
__device__ inline void sort16(int* v) {
    #pragma unroll
    for (int r = 0; r < 16; ++r) {
        #pragma unroll
        for (int i = r & 1; i + 1 < 16; i += 2) {
            int lo = min(v[i], v[i + 1]);
            int hi = max(v[i], v[i + 1]);
            v[i] = lo; v[i + 1] = hi;
        }
    }
}

// ---- weights -> Bck hi/lo bf16, layout [c][k], c in [0,2*D_OUT), k in [0,D_IN) ----
__global__ __launch_bounds__(256)
void prep_Bck(const float* __restrict__ W, unsigned short* __restrict__ Bhi,
              unsigned short* __restrict__ Blo, int D_IN, int D_OUT)
{
    int i = blockIdx.x * 256 + threadIdx.x;
    int total = 2 * D_OUT * D_IN;
    if (i >= total) return;
    int c = i / D_IN, k = i % D_IN;
    float v = (c < D_OUT) ? W[(size_t)c * (2 * D_IN) + k]
                          : W[(size_t)(c - D_OUT) * (2 * D_IN) + D_IN + k];
    unsigned short hi = bf16_rne(v);
    Bhi[i] = hi;
    Blo[i] = bf16_rne(v - bf16_tof(hi));
}

// ---- gemm1: dense, K=256, C=256. block = 64 nodes. full-K A in LDS. ----
__global__ __launch_bounds__(256, 2)
void gemm1(const float* __restrict__ hf,
           const unsigned short* __restrict__ Bhi,
           const unsigned short* __restrict__ Blo,
           float* __restrict__ gs, unsigned short* __restrict__ gn, int N)
{
    constexpr int K = 256, C = 256, DO = 128, LDA = 296;
    __shared__ unsigned short Ah[64 * LDA], Al[64 * LDA];

    const int tid  = threadIdx.x;
    const int wave = tid >> 6;
    const int lane = tid & 63;
    const int ml   = lane & 15;
    const int quad = lane >> 4;
    const int node0 = blockIdx.x * 64;

    // stage full-K A: 64 rows x 64 float4 chunks, split hi/lo
    #pragma unroll
    for (int t = 0; t < 16; ++t) {
        int idx = tid + t * 256;
        int row = idx >> 6, c4 = idx & 63;
        int nd = node0 + row; if (nd >= N) nd = N - 1;
        float4 v = *(const float4*)&hf[(size_t)nd * K + c4 * 4];
        float vv[4] = {v.x, v.y, v.z, v.w};
        unsigned short hi[4], lo[4];
        #pragma unroll
        for (int e = 0; e < 4; ++e) {
            hi[e] = bf16_rne(vv[e]);
            lo[e] = bf16_rne(vv[e] - bf16_tof(hi[e]));
        }
        *(uint2*)&Ah[row * LDA + c4 * 4] = *(const uint2*)hi;
        *(uint2*)&Al[row * LDA + c4 * 4] = *(const uint2*)lo;
    }
    __syncthreads();

    f32x4 acc[4][4];
    #pragma unroll
    for (int mi = 0; mi < 4; ++mi)
        #pragma unroll
        for (int ni = 0; ni < 4; ++ni)
            acc[mi][ni] = (f32x4){0.f, 0.f, 0.f, 0.f};

    for (int k0 = 0; k0 < K; k0 += 32) {
        short8 afh[4], afl[4];
        #pragma unroll
        for (int mi = 0; mi < 4; ++mi) {
            int r = mi * 16 + ml;
            afh[mi] = *(const short8*)&Ah[r * LDA + k0 + quad * 8];
            afl[mi] = *(const short8*)&Al[r * LDA + k0 + quad * 8];
        }
        #pragma unroll
        for (int ni = 0; ni < 4; ++ni) {
            int c = wave * 64 + ni * 16 + ml;
            short8 bh = *(const short8*)&Bhi[(size_t)c * K + k0 + quad * 8];
            short8 bl = *(const short8*)&Blo[(size_t)c * K + k0 + quad * 8];
            #pragma unroll
            for (int mi = 0; mi < 4; ++mi) {
                acc[mi][ni] = __builtin_amdgcn_mfma_f32_16x16x32_bf16(afl[mi], bh, acc[mi][ni], 0, 0, 0);
                acc[mi][ni] = __builtin_amdgcn_mfma_f32_16x16x32_bf16(afh[mi], bl, acc[mi][ni], 0, 0, 0);
                acc[mi][ni] = __builtin_amdgcn_mfma_f32_16x16x32_bf16(afh[mi], bh, acc[mi][ni], 0, 0, 0);
            }
        }
    }

    #pragma unroll
    for (int mi = 0; mi < 4; ++mi)
        #pragma unroll
        for (int r = 0; r < 4; ++r) {
            int node = node0 + mi * 16 + quad * 4 + r;
            if (node >= N) continue;
            #pragma unroll
            for (int ni = 0; ni < 4; ++ni) {
                int c = wave * 64 + ni * 16 + ml;
                float v = acc[mi][ni][r];
                if (c < DO) gs[(size_t)node * DO + c] = v;
                else        gn[(size_t)node * DO + (c - DO)] = bf16_rne(v);
            }
        }
}

// ---- fused layer: sorted-gather aggregate (A-phase) + barrier-free MFMA ----
template<int C>
__global__ __launch_bounds__(256, 3)
void fused_layer(const float* __restrict__ gs_in,
                 const unsigned short* __restrict__ gn_in,
                 const int* __restrict__ neigh,
                 const unsigned short* __restrict__ Bhi,
                 const unsigned short* __restrict__ Blo,
                 float* __restrict__ gs_out,
                 unsigned short* __restrict__ gn_out, int N)
{
    constexpr int K = 128, DO = C / 2, NI = C / 64, LDAF = 136;
    __shared__ unsigned short Afh[64 * LDAF], Afl[64 * LDAF];

    const int tid  = threadIdx.x;
    const int wave = tid >> 6;
    const int lane = tid & 63;
    const int ml   = lane & 15;
    const int quad = lane >> 4;
    const int node0 = blockIdx.x * 64;

    // ---- A-phase: h = relu(gs + mean*gn[nb]) with SORTED gathers ----
    {
        const int row = tid >> 2;          // node within block
        const int seg = tid & 3;           // 32-col segment
        int nd = node0 + row; if (nd >= N) nd = N - 1;
        const int4* nb4 = (const int4*)(neigh + (size_t)nd * FANOUT);
        int4 q0 = nb4[0], q1 = nb4[1], q2 = nb4[2], q3 = nb4[3];
        int ids[FANOUT] = {q0.x, q0.y, q0.z, q0.w, q1.x, q1.y, q1.z, q1.w,
                           q2.x, q2.y, q2.z, q2.w, q3.x, q3.y, q3.z, q3.w};
        sort16(ids);
        float acc[32];
        #pragma unroll
        for (int c = 0; c < 32; ++c) acc[c] = 0.f;
        #pragma unroll
        for (int j = 0; j < FANOUT; ++j) {
            const uint4* src = (const uint4*)&gn_in[(size_t)ids[j] * 128 + seg * 32];
            #pragma unroll
            for (int t = 0; t < 4; ++t) {
                uint4 q = src[t];
                acc[t*8+0] += __uint_as_float(q.x << 16);
                acc[t*8+1] += __uint_as_float(q.x & 0xffff0000u);
                acc[t*8+2] += __uint_as_float(q.y << 16);
                acc[t*8+3] += __uint_as_float(q.y & 0xffff0000u);
                acc[t*8+4] += __uint_as_float(q.z << 16);
                acc[t*8+5] += __uint_as_float(q.z & 0xffff0000u);
                acc[t*8+6] += __uint_as_float(q.w << 16);
                acc[t*8+7] += __uint_as_float(q.w & 0xffff0000u);
            }
        }
        const float inv = 1.0f / (float)FANOUT;
        alignas(16) unsigned short th[32], tl[32];
        const float4* gsp = (const float4*)&gs_in[(size_t)nd * 128 + seg * 32];
        #pragma unroll
        for (int t = 0; t < 8; ++t) {
            float4 s = gsp[t];
            float sv[4] = {s.x, s.y, s.z, s.w};
            #pragma unroll
            for (int e = 0; e < 4; ++e) {
                float h = fmaxf(fmaf(acc[t*4+e], inv, sv[e]), 0.f);
                unsigned short hi = bf16_rne(h);
                th[t*4+e] = hi;
                tl[t*4+e] = bf16_rne(h - bf16_tof(hi));
            }
        }
        #pragma unroll
        for (int t = 0; t < 4; ++t) {
            *(uint4*)&Afh[row * LDAF + seg * 32 + t * 8] = *(const uint4*)&th[t * 8];
            *(uint4*)&Afl[row * LDAF + seg * 32 + t * 8] = *(const uint4*)&tl[t * 8];
        }
    }
    __syncthreads();

    f32x4 acc[4][NI];
    #pragma unroll
    for (int mi = 0; mi < 4; ++mi)
        #pragma unroll
        for (int ni = 0; ni < NI; ++ni)
            acc[mi][ni] = (f32x4){0.f, 0.f, 0.f, 0.f};

    // barrier-free k-loop: A frags from LDS (read-only), B frags from L2
    for (int k0 = 0; k0 < K; k0 += 32) {
        short8 afh[4], afl[4];
        #pragma unroll
        for (int mi = 0; mi < 4; ++mi) {
            int r = mi * 16 + ml;
            afh[mi] = *(const short8*)&Afh[r * LDAF + k0 + quad * 8];
            afl[mi] = *(const short8*)&Afl[r * LDAF + k0 + quad * 8];
        }
        #pragma unroll
        for (int ni = 0; ni < NI; ++ni) {
            int c = wave * (16 * NI) + ni * 16 + ml;
            short8 bh = *(const short8*)&Bhi[(size_t)c * K + k0 + quad * 8];
            short8 bl = *(const short8*)&Blo[(size_t)c * K + k0 + quad * 8];
            #pragma unroll
            for (int mi = 0; mi < 4; ++mi) {
                acc[mi][ni] = __builtin_amdgcn_mfma_f32_16x16x32_bf16(afl[mi], bh, acc[mi][ni], 0, 0, 0);
                acc[mi][ni] = __builtin_amdgcn_mfma_f32_16x16x32_bf16(afh[mi], bl, acc[mi][ni], 0, 0, 0);
                acc[mi][ni] = __builtin_amdgcn_mfma_f32_16x16x32_bf16(afh[mi], bh, acc[mi][ni], 0, 0, 0);
            }
        }
    }

    #pragma unroll
    for (int mi = 0; mi < 4; ++mi)
        #pragma unroll
        for (int r = 0; r < 4; ++r) {
            int node = node0 + mi * 16 + quad * 4 + r;
            if (node >= N) continue;
            #pragma unroll
            for (int ni = 0; ni < NI; ++ni) {
                int c = wave * (16 * NI) + ni * 16 + ml;
                float v = acc[mi][ni][r];
                if (c < DO) gs_out[(size_t)node * DO + c] = v;
                else        gn_out[(size_t)node * DO + (c - DO)] = bf16_rne(v);
            }
        }
}

// ---- final: out[i] = relu(gs4[nodes[i]] + mean_j gn4[nb[j]]), D_OUT=64 ----
__global__ __launch_bounds__(256)
void agg_out(const float* __restrict__ gs4, const unsigned short* __restrict__ gn4,
             const int* __restrict__ neigh, const int* __restrict__ nodes,
             float* __restrict__ out, int N)
{
    const int i    = blockIdx.x * 32 + (threadIdx.x >> 3);
    const int lane = threadIdx.x & 7;
    if (i >= N) return;
    const int nd = nodes[i];
    const int4* nb4 = (const int4*)(neigh + (size_t)nd * FANOUT);
    int4 q0 = nb4[0], q1 = nb4[1], q2 = nb4[2], q3 = nb4[3];
    int ids[FANOUT] = {q0.x, q0.y, q0.z, q0.w, q1.x, q1.y, q1.z, q1.w,
                       q2.x, q2.y, q2.z, q2.w, q3.x, q3.y, q3.z, q3.w};
    sort16(ids);
    float acc[8];
    #pragma unroll
    for (int c = 0; c < 8; ++c) acc[c] = 0.f;
    #pragma unroll
    for (int j = 0; j < FANOUT; ++j) {
        uint4 q = *(const uint4*)&gn4[(size_t)ids[j] * 64 + lane * 8];
        acc[0] += __uint_as_float(q.x << 16);
        acc[1] += __uint_as_float(q.x & 0xffff0000u);
        acc[2] += __uint_as_float(q.y << 16);
        acc[3] += __uint_as_float(q.y & 0xffff0000u);
        acc[4] += __uint_as_float(q.z << 16);
        acc[5] += __uint_as_float(q.z & 0xffff0000u);
        acc[6] += __uint_as_float(q.w << 16);
        acc[7] += __uint_as_float(q.w & 0xffff0000u);
    }
    const float inv = 1.0f / (float)FANOUT;
    const float* s = gs4 + (size_t)nd * 64 + lane * 8;
    float4 s0 = *(const float4*)&s[0];
    float4 s1 = *(const float4*)&s[4];
    float4 o0, o1;
    o0.x = fmaxf(fmaf(acc[0], inv, s0.x), 0.f);
    o0.y = fmaxf(fmaf(acc[1], inv, s0.y), 0.f);
    o0.z = fmaxf(fmaf(acc[2], inv, s0.z), 0.f);
    o0.w = fmaxf(fmaf(acc[3], inv, s0.w), 0.f);
    o1.x = fmaxf(fmaf(acc[4], inv, s1.x), 0.f);
    o1.y = fmaxf(fmaf(acc[5], inv, s1.y), 0.f);
    o1.z = fmaxf(fmaf(acc[6], inv, s1.z), 0.f);
    o1.w = fmaxf(fmaf(acc[7], inv, s1.w), 0.f);
    float* op = out + (size_t)i * 64 + lane * 8;
    *(float4*)&op[0] = o0;
    *(float4*)&op[4] = o1;
}

extern "C" void kernel_launch(void* const* d_in, const int* in_sizes, int n_in,
                              void* d_out, int out_size, void* d_ws, size_t ws_size,
                              hipStream_t stream)
{
    const float* features = (const float*)d_in[0];
    const float* W1       = (const float*)d_in[1];
    const float* W2       = (const float*)d_in[2];
    const float* W3       = (const float*)d_in[3];
    const float* W4       = (const float*)d_in[4];
    const int*   nodes    = (const int*)d_in[5];
    const int*   neigh    = (const int*)d_in[6];
    float*       out      = (float*)d_out;

    unsigned short* B1h = (unsigned short*)d_ws;       // 65536
    unsigned short* B1l = B1h + 65536;
    unsigned short* B2h = B1l + 65536;                 // 32768
    unsigned short* B2l = B2h + 32768;
    unsigned short* B3h = B2l + 32768;
    unsigned short* B3l = B3h + 32768;
    unsigned short* B4h = B3l + 32768;                 // 16384
    unsigned short* B4l = B4h + 16384;
    float* gs = (float*)(B4l + 16384);                 // N*128 fp32, in-place L1-L3
    unsigned short* gnA = (unsigned short*)(gs + (size_t)N_NODES * 128); // N*128 bf16
    unsigned short* gnB = gnA + (size_t)N_NODES * 128; // N*128 bf16
    float* gs4 = (float*)gnB;                          // aliases gnB (free at L4)
    unsigned short* gn4 = gnB + (size_t)N_NODES * 128; // N*64 bf16

    prep_Bck<<<(65536 + 255) / 256, 256, 0, stream>>>(W1, B1h, B1l, 256, 128);
    prep_Bck<<<(32768 + 255) / 256, 256, 0, stream>>>(W2, B2h, B2l, 128, 128);
    prep_Bck<<<(32768 + 255) / 256, 256, 0, stream>>>(W3, B3h, B3l, 128, 128);
    prep_Bck<<<(16384 + 255) / 256, 256, 0, stream>>>(W4, B4h, B4l, 128, 64);

    const int grid = (N_NODES + 63) / 64;   // 1563

    gemm1<<<grid, 256, 0, stream>>>(features, B1h, B1l, gs, gnA, N_NODES);
    fused_layer<256><<<grid, 256, 0, stream>>>(gs, gnA, neigh, B2h, B2l, gs, gnB, N_NODES);
    fused_layer<256><<<grid, 256, 0, stream>>>(gs, gnB, neigh, B3h, B3l, gs, gnA, N_NODES);
    fused_layer<128><<<grid, 256, 0, stream>>>(gs, gnA, neigh, B4h, B4l, gs4, gn4, N_NODES);
    agg_out<<<(N_NODES + 31) / 32, 256, 0, stream>>>(gs4, gn4, neigh, nodes, out, N_NODES);
}

// Round 7
// 511.815 us; speedup vs baseline: 1.0514x; 1.0514x over previous
//
#include <hip/hip_runtime.h>
#include <hip/hip_bf16.h>

// GraphSAGE R7 = R5 structure (LDS-staged B everywhere — R6 lesson: at 2-3
// blocks/CU, cooperative LDS B-staging beats per-wave L2 frag reads) plus
// exactly ONE delta vs R5: sorted neighbor gathers (sort16) in fused_layer
// and agg_out, to A/B the gather-clustering theory cleanly.

constexpr int N_NODES = 100000;
constexpr int FANOUT  = 16;

typedef __attribute__((ext_vector_type(8))) short short8;
typedef __attribute__((ext_vector_type(4))) float f32x4;

__device__ inline unsigned short bf16_rne(float f) {
    unsigned u = __float_as_uint(f);
    return (unsigned short)((u + 0x7fffu + ((u >> 16) & 1u)) >> 16);
}
__device__ inline float bf16_tof(unsigned short s) {
    return __uint_as_float(((unsigned)s) << 16);
}

// branchless odd-even transposition sort, 16 ints in registers
__device__ inline void sort16(int* v) {
    #pragma unroll
    for (int r = 0; r < 16; ++r) {
        #pragma unroll
        for (int i = r & 1; i + 1 < 16; i += 2) {
            int lo = min(v[i], v[i + 1]);
            int hi = max(v[i], v[i + 1]);
            v[i] = lo; v[i + 1] = hi;
        }
    }
}

// ---- weights -> Bck hi/lo bf16, layout [c][k], c in [0,2*D_OUT), k in [0,D_IN) ----
__global__ __launch_bounds__(256)
void prep_Bck(const float* __restrict__ W, unsigned short* __restrict__ Bhi,
              unsigned short* __restrict__ Blo, int D_IN, int D_OUT)
{
    int i = blockIdx.x * 256 + threadIdx.x;
    int total = 2 * D_OUT * D_IN;
    if (i >= total) return;
    int c = i / D_IN, k = i % D_IN;
    float v = (c < D_OUT) ? W[(size_t)c * (2 * D_IN) + k]
                          : W[(size_t)(c - D_OUT) * (2 * D_IN) + D_IN + k];
    unsigned short hi = bf16_rne(v);
    Bhi[i] = hi;
    Blo[i] = bf16_rne(v - bf16_tof(hi));
}

// ---- gemm1: dense, K=256, C=256. block = 64 nodes, wave tile 64x64. ----
__global__ __launch_bounds__(256, 3)
void gemm1(const float* __restrict__ hf,
           const unsigned short* __restrict__ Bhi,
           const unsigned short* __restrict__ Blo,
           float* __restrict__ gs, unsigned short* __restrict__ gn, int N)
{
    constexpr int K = 256, C = 256, DO = 128, LDA = 40, LDB = 40;
    __shared__ unsigned short Ah[64 * LDA], Al[64 * LDA];
    __shared__ unsigned short Bh[C * LDB], Bl[C * LDB];

    const int tid  = threadIdx.x;
    const int wave = tid >> 6;
    const int lane = tid & 63;
    const int ml   = lane & 15;
    const int quad = lane >> 4;
    const int node0 = blockIdx.x * 64;

    f32x4 acc[4][4];
    #pragma unroll
    for (int mi = 0; mi < 4; ++mi)
        #pragma unroll
        for (int ni = 0; ni < 4; ++ni)
            acc[mi][ni] = (f32x4){0.f, 0.f, 0.f, 0.f};

    for (int k0 = 0; k0 < K; k0 += 32) {
        // A: 64 rows x 32 k fp32 -> split planes (512 float4, 2/thread)
        #pragma unroll
        for (int t = 0; t < 2; ++t) {
            int idx = tid + t * 256;
            int row = idx >> 3, c4 = idx & 7;
            int nd = node0 + row; if (nd >= N) nd = N - 1;
            float4 v = *(const float4*)&hf[(size_t)nd * K + k0 + c4 * 4];
            float vv[4] = {v.x, v.y, v.z, v.w};
            unsigned short hi[4], lo[4];
            #pragma unroll
            for (int e = 0; e < 4; ++e) {
                hi[e] = bf16_rne(vv[e]);
                lo[e] = bf16_rne(vv[e] - bf16_tof(hi[e]));
            }
            *(uint2*)&Ah[row * LDA + c4 * 4] = *(const uint2*)hi;
            *(uint2*)&Al[row * LDA + c4 * 4] = *(const uint2*)lo;
        }
        // B: 2 planes x 256 rows x 4 chunks (2048 uint4, 8/thread)
        #pragma unroll
        for (int t = 0; t < 8; ++t) {
            int idx = tid + t * 256;
            int pl  = idx >> 10;
            int rem = idx & 1023;
            int row = rem >> 2, ch = rem & 3;
            const unsigned short* src = (pl ? Blo : Bhi) + (size_t)row * K + k0 + ch * 8;
            unsigned short* dst = (pl ? Bl : Bh) + row * LDB + ch * 8;
            *(uint4*)dst = *(const uint4*)src;
        }
        __syncthreads();

        short8 afh[4], afl[4];
        #pragma unroll
        for (int mi = 0; mi < 4; ++mi) {
            int r = mi * 16 + ml;
            afh[mi] = *(const short8*)&Ah[r * LDA + quad * 8];
            afl[mi] = *(const short8*)&Al[r * LDA + quad * 8];
        }
        #pragma unroll
        for (int ni = 0; ni < 4; ++ni) {
            int c = wave * 64 + ni * 16 + ml;
            short8 bh = *(const short8*)&Bh[c * LDB + quad * 8];
            short8 bl = *(const short8*)&Bl[c * LDB + quad * 8];
            #pragma unroll
            for (int mi = 0; mi < 4; ++mi) {
                acc[mi][ni] = __builtin_amdgcn_mfma_f32_16x16x32_bf16(afl[mi], bh, acc[mi][ni], 0, 0, 0);
                acc[mi][ni] = __builtin_amdgcn_mfma_f32_16x16x32_bf16(afh[mi], bl, acc[mi][ni], 0, 0, 0);
                acc[mi][ni] = __builtin_amdgcn_mfma_f32_16x16x32_bf16(afh[mi], bh, acc[mi][ni], 0, 0, 0);
            }
        }
        __syncthreads();
    }

    #pragma unroll
    for (int mi = 0; mi < 4; ++mi)
        #pragma unroll
        for (int r = 0; r < 4; ++r) {
            int node = node0 + mi * 16 + quad * 4 + r;
            if (node >= N) continue;
            #pragma unroll
            for (int ni = 0; ni < 4; ++ni) {
                int c = wave * 64 + ni * 16 + ml;
                float v = acc[mi][ni][r];
                if (c < DO) gs[(size_t)node * DO + c] = v;
                else        gn[(size_t)node * DO + (c - DO)] = bf16_rne(v);
            }
        }
}

// ---- fused layer: sorted-gather aggregate (A-phase) + MFMA GEMM, B in LDS ----
template<int C>
__global__ __launch_bounds__(256, 2)
void fused_layer(const float* __restrict__ gs_in,
                 const unsigned short* __restrict__ gn_in,
                 const int* __restrict__ neigh,
                 const unsigned short* __restrict__ Bhi,
                 const unsigned short* __restrict__ Blo,
                 float* __restrict__ gs_out,
                 unsigned short* __restrict__ gn_out, int N)
{
    constexpr int K = 128, DO = C / 2, NI = C / 64, LDAF = 136, LDB = 40;
    __shared__ unsigned short Afh[64 * LDAF], Afl[64 * LDAF];
    __shared__ unsigned short Bh[C * LDB], Bl[C * LDB];

    const int tid  = threadIdx.x;
    const int wave = tid >> 6;
    const int lane = tid & 63;
    const int ml   = lane & 15;
    const int quad = lane >> 4;
    const int node0 = blockIdx.x * 64;

    // ---- A-phase: h = relu(gs + mean*gn[nb]) with SORTED gathers ----
    {
        const int row = tid >> 2;          // node within block
        const int seg = tid & 3;           // 32-col segment
        int nd = node0 + row; if (nd >= N) nd = N - 1;
        const int4* nb4 = (const int4*)(neigh + (size_t)nd * FANOUT);
        int4 q0 = nb4[0], q1 = nb4[1], q2 = nb4[2], q3 = nb4[3];
        int ids[FANOUT] = {q0.x, q0.y, q0.z, q0.w, q1.x, q1.y, q1.z, q1.w,
                           q2.x, q2.y, q2.z, q2.w, q3.x, q3.y, q3.z, q3.w};
        sort16(ids);
        float acc[32];
        #pragma unroll
        for (int c = 0; c < 32; ++c) acc[c] = 0.f;
        #pragma unroll
        for (int j = 0; j < FANOUT; ++j) {
            const uint4* src = (const uint4*)&gn_in[(size_t)ids[j] * 128 + seg * 32];
            #pragma unroll
            for (int t = 0; t < 4; ++t) {
                uint4 q = src[t];
                acc[t*8+0] += __uint_as_float(q.x << 16);
                acc[t*8+1] += __uint_as_float(q.x & 0xffff0000u);
                acc[t*8+2] += __uint_as_float(q.y << 16);
                acc[t*8+3] += __uint_as_float(q.y & 0xffff0000u);
                acc[t*8+4] += __uint_as_float(q.z << 16);
                acc[t*8+5] += __uint_as_float(q.z & 0xffff0000u);
                acc[t*8+6] += __uint_as_float(q.w << 16);
                acc[t*8+7] += __uint_as_float(q.w & 0xffff0000u);
            }
        }
        const float inv = 1.0f / (float)FANOUT;
        alignas(16) unsigned short th[32], tl[32];
        const float4* gsp = (const float4*)&gs_in[(size_t)nd * 128 + seg * 32];
        #pragma unroll
        for (int t = 0; t < 8; ++t) {
            float4 s = gsp[t];
            float sv[4] = {s.x, s.y, s.z, s.w};
            #pragma unroll
            for (int e = 0; e < 4; ++e) {
                float h = fmaxf(fmaf(acc[t*4+e], inv, sv[e]), 0.f);
                unsigned short hi = bf16_rne(h);
                th[t*4+e] = hi;
                tl[t*4+e] = bf16_rne(h - bf16_tof(hi));
            }
        }
        #pragma unroll
        for (int t = 0; t < 4; ++t) {
            *(uint4*)&Afh[row * LDAF + seg * 32 + t * 8] = *(const uint4*)&th[t * 8];
            *(uint4*)&Afl[row * LDAF + seg * 32 + t * 8] = *(const uint4*)&tl[t * 8];
        }
    }

    f32x4 acc[4][NI];
    #pragma unroll
    for (int mi = 0; mi < 4; ++mi)
        #pragma unroll
        for (int ni = 0; ni < NI; ++ni)
            acc[mi][ni] = (f32x4){0.f, 0.f, 0.f, 0.f};

    for (int k0 = 0; k0 < K; k0 += 32) {
        // stage B k-tile: 2 planes x C rows x 4 chunks
        constexpr int TOT = 2 * C * 4;
        #pragma unroll
        for (int t = 0; t < TOT / 256; ++t) {
            int idx = tid + t * 256;
            int pl  = idx / (C * 4);
            int rem = idx % (C * 4);
            int row = rem >> 2, ch = rem & 3;
            const unsigned short* src = (pl ? Blo : Bhi) + (size_t)row * K + k0 + ch * 8;
            unsigned short* dst = (pl ? Bl : Bh) + row * LDB + ch * 8;
            *(uint4*)dst = *(const uint4*)src;
        }
        __syncthreads();

        short8 afh[4], afl[4];
        #pragma unroll
        for (int mi = 0; mi < 4; ++mi) {
            int r = mi * 16 + ml;
            afh[mi] = *(const short8*)&Afh[r * LDAF + k0 + quad * 8];
            afl[mi] = *(const short8*)&Afl[r * LDAF + k0 + quad * 8];
        }
        #pragma unroll
        for (int ni = 0; ni < NI; ++ni) {
            int c = wave * (16 * NI) + ni * 16 + ml;
            short8 bh = *(const short8*)&Bh[c * LDB + quad * 8];
            short8 bl = *(const short8*)&Bl[c * LDB + quad * 8];
            #pragma unroll
            for (int mi = 0; mi < 4; ++mi) {
                acc[mi][ni] = __builtin_amdgcn_mfma_f32_16x16x32_bf16(afl[mi], bh, acc[mi][ni], 0, 0, 0);
                acc[mi][ni] = __builtin_amdgcn_mfma_f32_16x16x32_bf16(afh[mi], bl, acc[mi][ni], 0, 0, 0);
                acc[mi][ni] = __builtin_amdgcn_mfma_f32_16x16x32_bf16(afh[mi], bh, acc[mi][ni], 0, 0, 0);
            }
        }
        __syncthreads();
    }

    #pragma unroll
    for (int mi = 0; mi < 4; ++mi)
        #pragma unroll
        for (int r = 0; r < 4; ++r) {
            int node = node0 + mi * 16 + quad * 4 + r;
            if (node >= N) continue;
            #pragma unroll
            for (int ni = 0; ni < NI; ++ni) {
                int c = wave * (16 * NI) + ni * 16 + ml;
                float v = acc[mi][ni][r];
                if (c < DO) gs_out[(size_t)node * DO + c] = v;
                else        gn_out[(size_t)node * DO + (c - DO)] = bf16_rne(v);
            }
        }
}

// ---- final: out[i] = relu(gs4[nodes[i]] + mean_j gn4[nb[j]]), D_OUT=64 ----
__global__ __launch_bounds__(256)
void agg_out(const float* __restrict__ gs4, const unsigned short* __restrict__ gn4,
             const int* __restrict__ neigh, const int* __restrict__ nodes,
             float* __restrict__ out, int N)
{
    const int i    = blockIdx.x * 32 + (threadIdx.x >> 3);
    const int lane = threadIdx.x & 7;
    if (i >= N) return;
    const int nd = nodes[i];
    const int4* nb4 = (const int4*)(neigh + (size_t)nd * FANOUT);
    int4 q0 = nb4[0], q1 = nb4[1], q2 = nb4[2], q3 = nb4[3];
    int ids[FANOUT] = {q0.x, q0.y, q0.z, q0.w, q1.x, q1.y, q1.z, q1.w,
                       q2.x, q2.y, q2.z, q2.w, q3.x, q3.y, q3.z, q3.w};
    sort16(ids);
    float acc[8];
    #pragma unroll
    for (int c = 0; c < 8; ++c) acc[c] = 0.f;
    #pragma unroll
    for (int j = 0; j < FANOUT; ++j) {
        uint4 q = *(const uint4*)&gn4[(size_t)ids[j] * 64 + lane * 8];
        acc[0] += __uint_as_float(q.x << 16);
        acc[1] += __uint_as_float(q.x & 0xffff0000u);
        acc[2] += __uint_as_float(q.y << 16);
        acc[3] += __uint_as_float(q.y & 0xffff0000u);
        acc[4] += __uint_as_float(q.z << 16);
        acc[5] += __uint_as_float(q.z & 0xffff0000u);
        acc[6] += __uint_as_float(q.w << 16);
        acc[7] += __uint_as_float(q.w & 0xffff0000u);
    }
    const float inv = 1.0f / (float)FANOUT;
    const float* s = gs4 + (size_t)nd * 64 + lane * 8;
    float4 s0 = *(const float4*)&s[0];
    float4 s1 = *(const float4*)&s[4];
    float4 o0, o1;
    o0.x = fmaxf(fmaf(acc[0], inv, s0.x), 0.f);
    o0.y = fmaxf(fmaf(acc[1], inv, s0.y), 0.f);
    o0.z = fmaxf(fmaf(acc[2], inv, s0.z), 0.f);
    o0.w = fmaxf(fmaf(acc[3], inv, s0.w), 0.f);
    o1.x = fmaxf(fmaf(acc[4], inv, s1.x), 0.f);
    o1.y = fmaxf(fmaf(acc[5], inv, s1.y), 0.f);
    o1.z = fmaxf(fmaf(acc[6], inv, s1.z), 0.f);
    o1.w = fmaxf(fmaf(acc[7], inv, s1.w), 0.f);
    float* op = out + (size_t)i * 64 + lane * 8;
    *(float4*)&op[0] = o0;
    *(float4*)&op[4] = o1;
}

extern "C" void kernel_launch(void* const* d_in, const int* in_sizes, int n_in,
                              void* d_out, int out_size, void* d_ws, size_t ws_size,
                              hipStream_t stream)
{
    const float* features = (const float*)d_in[0];
    const float* W1       = (const float*)d_in[1];
    const float* W2       = (const float*)d_in[2];
    const float* W3       = (const float*)d_in[3];
    const float* W4       = (const float*)d_in[4];
    const int*   nodes    = (const int*)d_in[5];
    const int*   neigh    = (const int*)d_in[6];
    float*       out      = (float*)d_out;

    unsigned short* B1h = (unsigned short*)d_ws;       // 65536
    unsigned short* B1l = B1h + 65536;
    unsigned short* B2h = B1l + 65536;                 // 32768
    unsigned short* B2l = B2h + 32768;
    unsigned short* B3h = B2l + 32768;
    unsigned short* B3l = B3h + 32768;
    unsigned short* B4h = B3l + 32768;                 // 16384
    unsigned short* B4l = B4h + 16384;
    float* gs = (float*)(B4l + 16384);                 // N*128 fp32, in-place L1-L3
    unsigned short* gnA = (unsigned short*)(gs + (size_t)N_NODES * 128); // N*128 bf16
    unsigned short* gnB = gnA + (size_t)N_NODES * 128; // N*128 bf16
    float* gs4 = (float*)gnB;                          // aliases gnB (free at L4)
    unsigned short* gn4 = gnB + (size_t)N_NODES * 128; // N*64 bf16

    prep_Bck<<<(65536 + 255) / 256, 256, 0, stream>>>(W1, B1h, B1l, 256, 128);
    prep_Bck<<<(32768 + 255) / 256, 256, 0, stream>>>(W2, B2h, B2l, 128, 128);
    prep_Bck<<<(32768 + 255) / 256, 256, 0, stream>>>(W3, B3h, B3l, 128, 128);
    prep_Bck<<<(16384 + 255) / 256, 256, 0, stream>>>(W4, B4h, B4l, 128, 64);

    const int grid = (N_NODES + 63) / 64;   // 1563

    gemm1<<<grid, 256, 0, stream>>>(features, B1h, B1l, gs, gnA, N_NODES);
    fused_layer<256><<<grid, 256, 0, stream>>>(gs, gnA, neigh, B2h, B2l, gs, gnB, N_NODES);
    fused_layer<256><<<grid, 256, 0, stream>>>(gs, gnB, neigh, B3h, B3l, gs, gnA, N_NODES);
    fused_layer<128><<<grid, 256, 0, stream>>>(gs, gnA, neigh, B4h, B4l, gs4, gn4, N_NODES);
    agg_out<<<(N_NODES + 31) / 32, 256, 0, stream>>>(gs4, gn4, neigh, nodes, out, N_NODES);
}